// Round 9
// baseline (138.113 us; speedup 1.0000x reference)
//
#include <hip/hip_runtime.h>
#include <math.h>

#define NN 100000
#define NE 1600000
#define F_IN 64
#define HID 16
#define OUTF 32
#define BKT_SHIFT 6
#define BKT_NODES 64
#define NBKT 1563               // ceil(NN/64)
#define SRCM 0x1FFFF
#define CAP_REG 2048            // fixed region per bucket (mean 1024, sd 32)
#define CAP_LDS 1536            // fast-path LDS sort capacity
#define PBLK2 512
#define EPB2 (NE / PBLK2)       // 3125 (exact)
#define OVF_MAX 4096

__device__ __forceinline__ unsigned bf16r(float f) {   // round-to-nearest-even bf16 (finite)
    unsigned u = __float_as_uint(f);
    return (u + 0x7FFFu + ((u >> 16) & 1u)) >> 16;
}
__device__ __forceinline__ float bfa(unsigned p) { return __uint_as_float(p << 16); }
__device__ __forceinline__ float bfd(unsigned p) { return __uint_as_float(p & 0xFFFF0000u); }
__device__ __forceinline__ float bfh(unsigned short v) { return __uint_as_float(((unsigned)v) << 16); }

// ---- fused partition: hist -> scan -> claim -> LDS-sorted stage -> coalesced writeout ----
__global__ __launch_bounds__(1024) void partF_kernel(const int* __restrict__ ei,
                                                     const float* __restrict__ ea,
                                                     int* __restrict__ gcur,
                                                     int* __restrict__ novf,
                                                     int4* __restrict__ ovf,
                                                     int2* __restrict__ bkt) {
    __shared__ int hcnt[NBKT];                 // counts, then rank cursors
    __shared__ int hbase[NBKT];                // claimed global base per bucket
    __shared__ int lbase[NBKT];                // LDS base per bucket
    __shared__ int s[1024];
    __shared__ int2 sbuf[EPB2];                // 25 KB, bucket-sorted payloads
    __shared__ unsigned short bid[EPB2];       // 6.25 KB, bucket id per slot
    int t = threadIdx.x, blk = blockIdx.x;
    for (int i = t; i < NBKT; i += 1024) hcnt[i] = 0;
    __syncthreads();
    int beg = blk * EPB2, end = beg + EPB2;
    for (int e = beg + t; e < end; e += 1024)
        atomicAdd(&hcnt[ei[NE + e] >> BKT_SHIFT], 1);
    __syncthreads();
    // exclusive scan of hcnt -> lbase (2 elems/thread + Hillis-Steele)
    int i0 = 2 * t, i1 = 2 * t + 1;
    int v0 = (i0 < NBKT) ? hcnt[i0] : 0;
    int v1 = (i1 < NBKT) ? hcnt[i1] : 0;
    s[t] = v0 + v1;
    __syncthreads();
    for (int off = 1; off < 1024; off <<= 1) {
        int xv = (t >= off) ? s[t - off] : 0;
        __syncthreads();
        s[t] += xv;
        __syncthreads();
    }
    int run = (t == 0) ? 0 : s[t - 1];
    if (i0 < NBKT) lbase[i0] = run;
    if (i1 < NBKT) lbase[i1] = run + v0;
    __syncthreads();
    // claim global space; reset hcnt for rank pass
    for (int i = t; i < NBKT; i += 1024) {
        int c = hcnt[i];
        hbase[i] = c ? atomicAdd(&gcur[i], c) : 0;
        hcnt[i] = 0;
    }
    __syncthreads();
    // stage payloads bucket-sorted in LDS
    for (int e = beg + t; e < end; e += 1024) {
        int src = ei[e];
        int dst = ei[NE + e];
        float u = ea[e];
        int b = dst >> BKT_SHIFT;
        int r = atomicAdd(&hcnt[b], 1);
        int lp = lbase[b] + r;
        sbuf[lp] = make_int2(src | ((dst & (BKT_NODES - 1)) << 17), __float_as_int(u));
        bid[lp] = (unsigned short)b;
    }
    __syncthreads();
    // coalesced writeout: consecutive slots -> consecutive global addrs within runs
    for (int i = t; i < EPB2; i += 1024) {
        int2 pk = sbuf[i];
        int b = bid[i];
        int p = hbase[b] + (i - lbase[b]);
        if (p < CAP_REG) {
            bkt[(size_t)b * CAP_REG + p] = pk;
        } else {
            int o = atomicAdd(novf, 1);
            if (o < OVF_MAX)
                ovf[o] = make_int4(b * BKT_NODES + (pk.x >> 17), pk.x & SRCM, pk.y, 0);
        }
    }
}

// ---- layer-1 projection: ab1p = pack_bf16(a, b-a); r1 = x@root1 + bias1 (fp32) ----
__global__ __launch_bounds__(256) void proj1_kernel(const float* __restrict__ x,
                                                    const float* __restrict__ W1,
                                                    const float* __restrict__ root1,
                                                    const float* __restrict__ bias1,
                                                    unsigned* __restrict__ ab1p,
                                                    float* __restrict__ r1) {
    __shared__ float w[2 * F_IN * HID];
    __shared__ float wr[F_IN * HID];
    __shared__ float bb[HID];
    for (int i = threadIdx.x; i < 2 * F_IN * HID; i += 256) w[i] = W1[i];
    for (int i = threadIdx.x; i < F_IN * HID; i += 256) wr[i] = root1[i];
    if (threadIdx.x < HID) bb[threadIdx.x] = bias1[threadIdx.x];
    __syncthreads();
    int n = blockIdx.x * 256 + threadIdx.x;
    if (n >= NN) return;
    float accA[HID], accB[HID], accR[HID];
#pragma unroll
    for (int o = 0; o < HID; ++o) { accA[o] = 0.f; accB[o] = 0.f; accR[o] = bb[o]; }
    const float* xr = x + (size_t)n * F_IN;
    for (int f = 0; f < F_IN; ++f) {
        float xv = xr[f];
        const float* w0 = &w[f * HID];
        const float* w1 = &w[F_IN * HID + f * HID];
        const float* w2 = &wr[f * HID];
#pragma unroll
        for (int o = 0; o < HID; ++o) {
            accA[o] = fmaf(xv, w0[o], accA[o]);
            accB[o] = fmaf(xv, w1[o], accB[o]);
            accR[o] = fmaf(xv, w2[o], accR[o]);
        }
    }
    unsigned* ar = ab1p + (size_t)n * HID;
    float* rr = r1 + (size_t)n * HID;
#pragma unroll
    for (int o = 0; o < HID; ++o) {
        ar[o] = bf16r(accA[o]) | (bf16r(accB[o] - accA[o]) << 16);
        rr[o] = accR[o];
    }
}

// ---- layer-1: LDS counting-sort + register accumulate + ELU -> h16; persist sorted+segg ----
__global__ __launch_bounds__(512) void gather1_kernel(const int* __restrict__ gcur,
                                                      const int* __restrict__ novf,
                                                      const int4* __restrict__ ovf,
                                                      int2* __restrict__ bkt,
                                                      const unsigned* __restrict__ ab1p,
                                                      const float* __restrict__ r1,
                                                      unsigned short* __restrict__ h16,
                                                      float* __restrict__ dinv,
                                                      int* __restrict__ segg) {
    __shared__ int2 sorted[CAP_LDS];        // 12 KB
    __shared__ int cnt[BKT_NODES], cur[BKT_NODES], segb[BKT_NODES + 1];
    __shared__ float accL[BKT_NODES * HID];
    __shared__ float degsL[BKT_NODES];
    int t = threadIdx.x;
    int b = blockIdx.x;
    int tot = gcur[b];
    int beg = b * CAP_REG;
    if (t < BKT_NODES) { cnt[t] = 0; cur[t] = 0; degsL[t] = 0.f; }
    __syncthreads();
    int nodeBase = b * BKT_NODES;

    if (tot <= CAP_LDS) {
        int end = beg + tot;
        for (int e = beg + t; e < end; e += 512)
            atomicAdd(&cnt[((unsigned)bkt[e].x) >> 17], 1);
        __syncthreads();
        if (t < BKT_NODES) {
            int v = cnt[t];
            int sc = v;
#pragma unroll
            for (int off = 1; off < 64; off <<= 1) {
                int o = __shfl_up(sc, off, 64);
                if (t >= off) sc += o;
            }
            segb[t] = sc - v;
            if (t == 63) segb[64] = sc;
        }
        __syncthreads();
        for (int e = beg + t; e < end; e += 512) {
            int2 pk = bkt[e];
            int loc = ((unsigned)pk.x) >> 17;
            int pos = segb[loc] + atomicAdd(&cur[loc], 1);
            sorted[pos] = pk;
        }
        __syncthreads();
        // persist sorted order + segment bounds for gather2
        for (int e = t; e < tot; e += 512) bkt[beg + e] = sorted[e];
        if (t <= BKT_NODES) segg[b * (BKT_NODES + 1) + t] = segb[t];
        int j = t & (HID - 1);
        int g = t >> 4;                 // 32 groups, nodes 2g, 2g+1
        int s = segb[2 * g], mid = segb[2 * g + 1], e2 = segb[2 * g + 2];
        float a0 = 0.f, a1 = 0.f;
        int e = s;
        for (; e + 8 <= e2; e += 8) {
            float val[8]; int sel[8];
#pragma unroll
            for (int k = 0; k < 8; ++k) {
                int2 pk = sorted[e + k];
                unsigned p = ab1p[(size_t)(pk.x & SRCM) * HID + j];
                val[k] = fmaf(__int_as_float(pk.y), bfd(p), bfa(p));
                sel[k] = (e + k) >= mid;
            }
#pragma unroll
            for (int k = 0; k < 8; ++k) {
                a0 += sel[k] ? 0.f : val[k];
                a1 += sel[k] ? val[k] : 0.f;
            }
        }
        for (; e < e2; ++e) {
            int2 pk = sorted[e];
            unsigned p = ab1p[(size_t)(pk.x & SRCM) * HID + j];
            float val = fmaf(__int_as_float(pk.y), bfd(p), bfa(p));
            if (e >= mid) a1 += val; else a0 += val;
        }
        float d0 = 1.f / (float)max(mid - s, 1);
        float d1 = 1.f / (float)max(e2 - mid, 1);
        int n0 = nodeBase + 2 * g, n1 = n0 + 1;
        if (n0 < NN) {
            float v = a0 * d0 + r1[(size_t)n0 * HID + j];
            h16[(size_t)n0 * HID + j] = (unsigned short)bf16r(v > 0.f ? v : expm1f(v));
            if (j == 0) dinv[n0] = d0;
        }
        if (n1 < NN) {
            float v = a1 * d1 + r1[(size_t)n1 * HID + j];
            h16[(size_t)n1 * HID + j] = (unsigned short)bf16r(v > 0.f ? v : expm1f(v));
            if (j == 0) dinv[n1] = d1;
        }
    } else {
        // ---- legacy atomic path (bucket overflow; statistically never) ----
        int inreg = min(tot, CAP_REG);
        int end = beg + inreg;
        for (int i = t; i < BKT_NODES * HID; i += 512) accL[i] = 0.f;
        __syncthreads();
        int j = t & (HID - 1);
        int g = t >> 4;
        for (int e = beg + g; e < end; e += 32) {
            int2 pk = bkt[e];
            unsigned p = ab1p[(size_t)(pk.x & SRCM) * HID + j];
            atomicAdd(&accL[(((unsigned)pk.x) >> 17) * HID + j],
                      fmaf(__int_as_float(pk.y), bfd(p), bfa(p)));
            if (j == 0) atomicAdd(&degsL[((unsigned)pk.x) >> 17], 1.f);
        }
        int ovn = min(novf[0], OVF_MAX);
        for (int o = 0; o < ovn; ++o) {
            int4 ent = ovf[o];
            int loc = ent.x - nodeBase;
            if (loc >= 0 && loc < BKT_NODES && g == 0) {
                unsigned p = ab1p[(size_t)ent.y * HID + j];
                atomicAdd(&accL[loc * HID + j], fmaf(__int_as_float(ent.z), bfd(p), bfa(p)));
                if (j == 0) atomicAdd(&degsL[loc], 1.f);
            }
        }
        __syncthreads();
        if (t < BKT_NODES) degsL[t] = 1.f / fmaxf(degsL[t], 1.f);
        __syncthreads();
#pragma unroll
        for (int it = 0; it < BKT_NODES * HID / 512; ++it) {
            int idx = it * 512 + t;
            int nl = idx >> 4, jj = idx & (HID - 1);
            int n = nodeBase + nl;
            if (n < NN) {
                float v = accL[idx] * degsL[nl] + r1[(size_t)n * HID + jj];
                h16[(size_t)n * HID + jj] = (unsigned short)bf16r(v > 0.f ? v : expm1f(v));
            }
        }
        if (t < BKT_NODES && nodeBase + t < NN) dinv[nodeBase + t] = degsL[t];
    }
}

// ---- layer-2: stream pre-sorted bucket from global; S0=Σh, S1=Σu·h; project + log_softmax ----
__global__ __launch_bounds__(512) void gather2_kernel(const int* __restrict__ gcur,
                                                      const int* __restrict__ novf,
                                                      const int4* __restrict__ ovf,
                                                      const int2* __restrict__ bkt,
                                                      const unsigned short* __restrict__ h16,
                                                      const float* __restrict__ W2,
                                                      const float* __restrict__ root2,
                                                      const float* __restrict__ bias2,
                                                      const float* __restrict__ dinv,
                                                      const int* __restrict__ segg,
                                                      float* __restrict__ out) {
    __shared__ int segb[BKT_NODES + 1];
    __shared__ float s0L[BKT_NODES * HID];  // 4 KB
    __shared__ float s1L[BKT_NODES * HID];  // 4 KB
    __shared__ float w20[HID * OUTF], w2d[HID * OUTF], wr[HID * OUTF];
    __shared__ float bb[OUTF];
    int t = threadIdx.x;
    for (int i = t; i < HID * OUTF; i += 512) {
        float a = W2[i];
        w20[i] = a;
        w2d[i] = W2[HID * OUTF + i] - a;
        wr[i] = root2[i];
    }
    if (t < OUTF) bb[t] = bias2[t];
    int b = blockIdx.x;
    int tot = gcur[b];
    int beg = b * CAP_REG;
    int nodeBase = b * BKT_NODES;
    if (t <= BKT_NODES) segb[t] = segg[b * (BKT_NODES + 1) + t];
    __syncthreads();

    if (tot <= CAP_LDS) {
        const int2* sp = bkt + beg;   // pre-sorted by gather1
        int j = t & (HID - 1);
        int g = t >> 4;
        int s = segb[2 * g], mid = segb[2 * g + 1], e2 = segb[2 * g + 2];
        float s00 = 0.f, s10 = 0.f, s01 = 0.f, s11 = 0.f;
        int e = s;
        for (; e + 8 <= e2; e += 8) {
            float hv[8], uv[8]; int sel[8];
#pragma unroll
            for (int k = 0; k < 8; ++k) {
                int2 pk = sp[e + k];
                hv[k] = bfh(h16[(size_t)(pk.x & SRCM) * HID + j]);
                uv[k] = __int_as_float(pk.y);
                sel[k] = (e + k) >= mid;
            }
#pragma unroll
            for (int k = 0; k < 8; ++k) {
                float uh = uv[k] * hv[k];
                s00 += sel[k] ? 0.f : hv[k];
                s10 += sel[k] ? 0.f : uh;
                s01 += sel[k] ? hv[k] : 0.f;
                s11 += sel[k] ? uh : 0.f;
            }
        }
        for (; e < e2; ++e) {
            int2 pk = sp[e];
            float hvv = bfh(h16[(size_t)(pk.x & SRCM) * HID + j]);
            float uh = __int_as_float(pk.y) * hvv;
            if (e >= mid) { s01 += hvv; s11 += uh; }
            else          { s00 += hvv; s10 += uh; }
        }
        s0L[(2 * g) * HID + j] = s00;
        s1L[(2 * g) * HID + j] = s10;
        s0L[(2 * g + 1) * HID + j] = s01;
        s1L[(2 * g + 1) * HID + j] = s11;
        __syncthreads();
    } else {
        int inreg = min(tot, CAP_REG);
        int end = beg + inreg;
        for (int i = t; i < BKT_NODES * HID; i += 512) { s0L[i] = 0.f; s1L[i] = 0.f; }
        __syncthreads();
        int j = t & (HID - 1);
        int g = t >> 4;
        for (int e = beg + g; e < end; e += 32) {
            int2 pk = bkt[e];
            float hvv = bfh(h16[(size_t)(pk.x & SRCM) * HID + j]);
            int l = ((unsigned)pk.x) >> 17;
            atomicAdd(&s0L[l * HID + j], hvv);
            atomicAdd(&s1L[l * HID + j], __int_as_float(pk.y) * hvv);
        }
        int ovn = min(novf[0], OVF_MAX);
        for (int o = 0; o < ovn; ++o) {
            int4 ent = ovf[o];
            int loc = ent.x - nodeBase;
            if (loc >= 0 && loc < BKT_NODES && g == 0) {
                float hvv = bfh(h16[(size_t)ent.y * HID + j]);
                atomicAdd(&s0L[loc * HID + j], hvv);
                atomicAdd(&s1L[loc * HID + j], __int_as_float(ent.z) * hvv);
            }
        }
        __syncthreads();
    }

#pragma unroll
    for (int it = 0; it < BKT_NODES * OUTF / 512; ++it) {  // 4
        int idx = it * 512 + t;
        int nl = idx >> 5, jj = idx & (OUTF - 1);
        int n = nodeBase + nl;
        float v = 0.f;
        if (n < NN) {
            float msum = 0.f;
            const float* S0 = &s0L[nl * HID];
            const float* S1 = &s1L[nl * HID];
#pragma unroll
            for (int f = 0; f < HID; ++f)
                msum += S0[f] * w20[f * OUTF + jj] + S1[f] * w2d[f * OUTF + jj];
            v = msum * dinv[n] + bb[jj];
            const unsigned short* hr = h16 + (size_t)n * HID;
#pragma unroll
            for (int f = 0; f < HID; ++f)
                v = fmaf(bfh(hr[f]), wr[f * OUTF + jj], v);
        }
        float m = v;
#pragma unroll
        for (int mask = 16; mask >= 1; mask >>= 1) m = fmaxf(m, __shfl_xor(m, mask));
        float ex = expf(v - m);
        float sm = ex;
#pragma unroll
        for (int mask = 16; mask >= 1; mask >>= 1) sm += __shfl_xor(sm, mask);
        if (n < NN) out[(size_t)n * OUTF + jj] = v - m - logf(sm);
    }
}

extern "C" void kernel_launch(void* const* d_in, const int* in_sizes, int n_in,
                              void* d_out, int out_size, void* d_ws, size_t ws_size,
                              hipStream_t stream) {
    const float* x     = (const float*)d_in[0];
    const int*   ei    = (const int*)d_in[1];
    const float* ea    = (const float*)d_in[3];
    const float* W1    = (const float*)d_in[4];
    const float* root1 = (const float*)d_in[5];
    const float* bias1 = (const float*)d_in[6];
    const float* W2    = (const float*)d_in[7];
    const float* root2 = (const float*)d_in[8];
    const float* bias2 = (const float*)d_in[9];
    float* out = (float*)d_out;
    float* ws  = (float*)d_ws;

    const size_t N = NN;
    // workspace (float units), total ~10.63M floats ≈ 42.5 MB
    int*            gcur = (int*)(ws);                        // 1563
    int*            novf = (int*)(ws + 2000);                 // 1
    int4*           ovf  = (int4*)(ws + 2048);                // OVF_MAX int4
    float*          dinv = ws + 20000;                        // 100000
    int*            segg = (int*)(ws + 120000);               // NBKT*65 = 101595
    float*          r1   = ws + 222000;                       // 16N
    unsigned*       ab1p = (unsigned*)(ws + 222000 + 16 * N); // 16N u32
    unsigned short* h16  = (unsigned short*)(ws + 222000 + 32 * N); // 16N u16
    int2*           bkt  = (int2*)(ws + 222000 + 40 * N);     // NBKT*CAP_REG int2

    hipMemsetAsync(gcur, 0, 8448, stream);  // gcur + novf

    int nbN = (NN + 255) / 256;
    partF_kernel<<<PBLK2, 1024, 0, stream>>>(ei, ea, gcur, novf, ovf, bkt);
    proj1_kernel<<<nbN, 256, 0, stream>>>(x, W1, root1, bias1, ab1p, r1);
    gather1_kernel<<<NBKT, 512, 0, stream>>>(gcur, novf, ovf, bkt, ab1p, r1, h16, dinv, segg);
    gather2_kernel<<<NBKT, 512, 0, stream>>>(gcur, novf, ovf, bkt, h16, W2, root2, bias2, dinv, segg, out);
}

// Round 10
// 127.292 us; speedup vs baseline: 1.0850x; 1.0850x over previous
//
#include <hip/hip_runtime.h>
#include <math.h>

#define NN 100000
#define NE 1600000
#define F_IN 64
#define HID 16
#define OUTF 32
#define BKT_SHIFT 6
#define BKT_NODES 64
#define NBKT 1563               // ceil(NN/64)
#define SRCM 0x1FFFF
#define CAP_REG 2048            // fixed region per bucket (mean 1024, sd 32)
#define CAP_LDS 1536            // fast-path LDS sort capacity
#define PBLK2 512
#define EPB2 (NE / PBLK2)       // 3125 (exact)
#define OVF_MAX 4096

__device__ __forceinline__ unsigned bf16r(float f) {   // round-to-nearest-even bf16 (finite)
    unsigned u = __float_as_uint(f);
    return (u + 0x7FFFu + ((u >> 16) & 1u)) >> 16;
}
__device__ __forceinline__ float bfa(unsigned p) { return __uint_as_float(p << 16); }
__device__ __forceinline__ float bfd(unsigned p) { return __uint_as_float(p & 0xFFFF0000u); }
__device__ __forceinline__ float bfh(unsigned short v) { return __uint_as_float(((unsigned)v) << 16); }

// ---- zero gcur/novf (replaces pathological hipMemsetAsync fill kernel) ----
__global__ __launch_bounds__(256) void zeroG_kernel(int* __restrict__ gcur,
                                                    int* __restrict__ novf) {
    int t = blockIdx.x * 256 + threadIdx.x;
    if (t < NBKT) gcur[t] = 0;
    if (t == NBKT) novf[0] = 0;
}

// ---- fused partition: hist -> scan -> claim -> LDS-sorted stage -> coalesced writeout ----
__global__ __launch_bounds__(1024) void partF_kernel(const int* __restrict__ ei,
                                                     const float* __restrict__ ea,
                                                     int* __restrict__ gcur,
                                                     int* __restrict__ novf,
                                                     int4* __restrict__ ovf,
                                                     int2* __restrict__ bkt) {
    __shared__ int hcnt[NBKT];                 // counts, then rank cursors
    __shared__ int hbase[NBKT];                // claimed global base per bucket
    __shared__ int lbase[NBKT];                // LDS base per bucket
    __shared__ int s[1024];
    __shared__ int2 sbuf[EPB2];                // 25 KB, bucket-sorted payloads
    __shared__ unsigned short bid[EPB2];       // 6.25 KB, bucket id per slot
    int t = threadIdx.x, blk = blockIdx.x;
    for (int i = t; i < NBKT; i += 1024) hcnt[i] = 0;
    __syncthreads();
    int beg = blk * EPB2, end = beg + EPB2;
    for (int e = beg + t; e < end; e += 1024)
        atomicAdd(&hcnt[ei[NE + e] >> BKT_SHIFT], 1);
    __syncthreads();
    int i0 = 2 * t, i1 = 2 * t + 1;
    int v0 = (i0 < NBKT) ? hcnt[i0] : 0;
    int v1 = (i1 < NBKT) ? hcnt[i1] : 0;
    s[t] = v0 + v1;
    __syncthreads();
    for (int off = 1; off < 1024; off <<= 1) {
        int xv = (t >= off) ? s[t - off] : 0;
        __syncthreads();
        s[t] += xv;
        __syncthreads();
    }
    int run = (t == 0) ? 0 : s[t - 1];
    if (i0 < NBKT) lbase[i0] = run;
    if (i1 < NBKT) lbase[i1] = run + v0;
    __syncthreads();
    for (int i = t; i < NBKT; i += 1024) {
        int c = hcnt[i];
        hbase[i] = c ? atomicAdd(&gcur[i], c) : 0;
        hcnt[i] = 0;
    }
    __syncthreads();
    for (int e = beg + t; e < end; e += 1024) {
        int src = ei[e];
        int dst = ei[NE + e];
        float u = ea[e];
        int b = dst >> BKT_SHIFT;
        int r = atomicAdd(&hcnt[b], 1);
        int lp = lbase[b] + r;
        sbuf[lp] = make_int2(src | ((dst & (BKT_NODES - 1)) << 17), __float_as_int(u));
        bid[lp] = (unsigned short)b;
    }
    __syncthreads();
    for (int i = t; i < EPB2; i += 1024) {
        int2 pk = sbuf[i];
        int b = bid[i];
        int p = hbase[b] + (i - lbase[b]);
        if (p < CAP_REG) {
            bkt[(size_t)b * CAP_REG + p] = pk;
        } else {
            int o = atomicAdd(novf, 1);
            if (o < OVF_MAX)
                ovf[o] = make_int4(b * BKT_NODES + (pk.x >> 17), pk.x & SRCM, pk.y, 0);
        }
    }
}

// ---- layer-1 projection: ab1p = pack_bf16(a, b-a); r1 = x@root1 + bias1 (fp32) ----
__global__ __launch_bounds__(256) void proj1_kernel(const float* __restrict__ x,
                                                    const float* __restrict__ W1,
                                                    const float* __restrict__ root1,
                                                    const float* __restrict__ bias1,
                                                    unsigned* __restrict__ ab1p,
                                                    float* __restrict__ r1) {
    __shared__ float w[2 * F_IN * HID];
    __shared__ float wr[F_IN * HID];
    __shared__ float bb[HID];
    for (int i = threadIdx.x; i < 2 * F_IN * HID; i += 256) w[i] = W1[i];
    for (int i = threadIdx.x; i < F_IN * HID; i += 256) wr[i] = root1[i];
    if (threadIdx.x < HID) bb[threadIdx.x] = bias1[threadIdx.x];
    __syncthreads();
    int n = blockIdx.x * 256 + threadIdx.x;
    if (n >= NN) return;
    float accA[HID], accB[HID], accR[HID];
#pragma unroll
    for (int o = 0; o < HID; ++o) { accA[o] = 0.f; accB[o] = 0.f; accR[o] = bb[o]; }
    const float* xr = x + (size_t)n * F_IN;
    for (int f = 0; f < F_IN; ++f) {
        float xv = xr[f];
        const float* w0 = &w[f * HID];
        const float* w1 = &w[F_IN * HID + f * HID];
        const float* w2 = &wr[f * HID];
#pragma unroll
        for (int o = 0; o < HID; ++o) {
            accA[o] = fmaf(xv, w0[o], accA[o]);
            accB[o] = fmaf(xv, w1[o], accB[o]);
            accR[o] = fmaf(xv, w2[o], accR[o]);
        }
    }
    unsigned* ar = ab1p + (size_t)n * HID;
    float* rr = r1 + (size_t)n * HID;
#pragma unroll
    for (int o = 0; o < HID; ++o) {
        ar[o] = bf16r(accA[o]) | (bf16r(accB[o] - accA[o]) << 16);
        rr[o] = accR[o];
    }
}

// ---- layer-1: LDS stage + counting-sort + per-node register loops + ELU -> h16 ----
__global__ __launch_bounds__(512) void gather1_kernel(const int* __restrict__ gcur,
                                                      const int* __restrict__ novf,
                                                      const int4* __restrict__ ovf,
                                                      int2* __restrict__ bkt,
                                                      const unsigned* __restrict__ ab1p,
                                                      const float* __restrict__ r1,
                                                      unsigned short* __restrict__ h16,
                                                      float* __restrict__ dinv,
                                                      int* __restrict__ segg) {
    __shared__ int2 raw[CAP_LDS];           // 12 KB
    __shared__ int2 sorted[CAP_LDS];        // 12 KB
    __shared__ int cnt[BKT_NODES], cur[BKT_NODES], segb[BKT_NODES + 1];
    __shared__ float degsL[BKT_NODES];      // legacy path
    int t = threadIdx.x;
    int b = blockIdx.x;
    int tot = gcur[b];
    int beg = b * CAP_REG;
    if (t < BKT_NODES) { cnt[t] = 0; cur[t] = 0; degsL[t] = 0.f; }
    __syncthreads();
    int nodeBase = b * BKT_NODES;

    if (tot <= CAP_LDS) {
        for (int e = t; e < tot; e += 512) raw[e] = bkt[beg + e];
        __syncthreads();
        for (int e = t; e < tot; e += 512)
            atomicAdd(&cnt[((unsigned)raw[e].x) >> 17], 1);
        __syncthreads();
        if (t < BKT_NODES) {
            int v = cnt[t];
            int sc = v;
#pragma unroll
            for (int off = 1; off < 64; off <<= 1) {
                int o = __shfl_up(sc, off, 64);
                if (t >= off) sc += o;
            }
            segb[t] = sc - v;
            if (t == 63) segb[64] = sc;
        }
        __syncthreads();
        for (int e = t; e < tot; e += 512) {
            int2 pk = raw[e];
            int loc = ((unsigned)pk.x) >> 17;
            int pos = segb[loc] + atomicAdd(&cur[loc], 1);
            sorted[pos] = pk;
        }
        __syncthreads();
        // persist sorted order + segment bounds for gather2
        for (int e = t; e < tot; e += 512) bkt[beg + e] = sorted[e];
        if (t <= BKT_NODES) segg[b * (BKT_NODES + 1) + t] = segb[t];
        int j = t & (HID - 1);
        int g = t >> 4;                 // 32 groups, nodes 2g, 2g+1
        int s = segb[2 * g], mid = segb[2 * g + 1], e2 = segb[2 * g + 2];
        float a0 = 0.f, a1 = 0.f;
        int e = s;
        for (; e + 8 <= mid; e += 8) {
            float val[8];
#pragma unroll
            for (int k = 0; k < 8; ++k) {
                int2 pk = sorted[e + k];
                unsigned p = ab1p[(size_t)(pk.x & SRCM) * HID + j];
                val[k] = fmaf(__int_as_float(pk.y), bfd(p), bfa(p));
            }
#pragma unroll
            for (int k = 0; k < 8; ++k) a0 += val[k];
        }
        for (; e < mid; ++e) {
            int2 pk = sorted[e];
            unsigned p = ab1p[(size_t)(pk.x & SRCM) * HID + j];
            a0 += fmaf(__int_as_float(pk.y), bfd(p), bfa(p));
        }
        for (; e + 8 <= e2; e += 8) {
            float val[8];
#pragma unroll
            for (int k = 0; k < 8; ++k) {
                int2 pk = sorted[e + k];
                unsigned p = ab1p[(size_t)(pk.x & SRCM) * HID + j];
                val[k] = fmaf(__int_as_float(pk.y), bfd(p), bfa(p));
            }
#pragma unroll
            for (int k = 0; k < 8; ++k) a1 += val[k];
        }
        for (; e < e2; ++e) {
            int2 pk = sorted[e];
            unsigned p = ab1p[(size_t)(pk.x & SRCM) * HID + j];
            a1 += fmaf(__int_as_float(pk.y), bfd(p), bfa(p));
        }
        float d0 = 1.f / (float)max(mid - s, 1);
        float d1 = 1.f / (float)max(e2 - mid, 1);
        int n0 = nodeBase + 2 * g, n1 = n0 + 1;
        if (n0 < NN) {
            float v = a0 * d0 + r1[(size_t)n0 * HID + j];
            h16[(size_t)n0 * HID + j] = (unsigned short)bf16r(v > 0.f ? v : expm1f(v));
            if (j == 0) dinv[n0] = d0;
        }
        if (n1 < NN) {
            float v = a1 * d1 + r1[(size_t)n1 * HID + j];
            h16[(size_t)n1 * HID + j] = (unsigned short)bf16r(v > 0.f ? v : expm1f(v));
            if (j == 0) dinv[n1] = d1;
        }
    } else {
        // ---- legacy atomic path (bucket overflow; statistically never) ----
        float* accL = (float*)raw;  // reuse 12 KB as 1024-float accum (BKT_NODES*HID)
        int inreg = min(tot, CAP_REG);
        int end = beg + inreg;
        for (int i = t; i < BKT_NODES * HID; i += 512) accL[i] = 0.f;
        __syncthreads();
        int j = t & (HID - 1);
        int g = t >> 4;
        for (int e = beg + g; e < end; e += 32) {
            int2 pk = bkt[e];
            unsigned p = ab1p[(size_t)(pk.x & SRCM) * HID + j];
            atomicAdd(&accL[(((unsigned)pk.x) >> 17) * HID + j],
                      fmaf(__int_as_float(pk.y), bfd(p), bfa(p)));
            if (j == 0) atomicAdd(&degsL[((unsigned)pk.x) >> 17], 1.f);
        }
        int ovn = min(novf[0], OVF_MAX);
        for (int o = 0; o < ovn; ++o) {
            int4 ent = ovf[o];
            int loc = ent.x - nodeBase;
            if (loc >= 0 && loc < BKT_NODES && g == 0) {
                unsigned p = ab1p[(size_t)ent.y * HID + j];
                atomicAdd(&accL[loc * HID + j], fmaf(__int_as_float(ent.z), bfd(p), bfa(p)));
                if (j == 0) atomicAdd(&degsL[loc], 1.f);
            }
        }
        __syncthreads();
        if (t < BKT_NODES) degsL[t] = 1.f / fmaxf(degsL[t], 1.f);
        // mark "unsorted" for gather2 by segg[...0] = -1
        if (t == 0) segg[b * (BKT_NODES + 1)] = -1;
        __syncthreads();
#pragma unroll
        for (int it = 0; it < BKT_NODES * HID / 512; ++it) {
            int idx = it * 512 + t;
            int nl = idx >> 4, jj = idx & (HID - 1);
            int n = nodeBase + nl;
            if (n < NN) {
                float v = accL[idx] * degsL[nl] + r1[(size_t)n * HID + jj];
                h16[(size_t)n * HID + jj] = (unsigned short)bf16r(v > 0.f ? v : expm1f(v));
            }
        }
        if (t < BKT_NODES && nodeBase + t < NN) dinv[nodeBase + t] = degsL[t];
    }
}

// ---- layer-2: LDS stage of pre-sorted bucket; per-node loops; project + log_softmax ----
__global__ __launch_bounds__(512) void gather2_kernel(const int* __restrict__ gcur,
                                                      const int* __restrict__ novf,
                                                      const int4* __restrict__ ovf,
                                                      const int2* __restrict__ bkt,
                                                      const unsigned short* __restrict__ h16,
                                                      const float* __restrict__ W2,
                                                      const float* __restrict__ root2,
                                                      const float* __restrict__ bias2,
                                                      const float* __restrict__ dinv,
                                                      const int* __restrict__ segg,
                                                      float* __restrict__ out) {
    __shared__ int2 sbufL[CAP_LDS];         // 12 KB (pre-sorted payloads)
    __shared__ int segb[BKT_NODES + 1];
    __shared__ float s0L[BKT_NODES * HID];  // 4 KB
    __shared__ float s1L[BKT_NODES * HID];  // 4 KB
    __shared__ float w20[HID * OUTF], w2d[HID * OUTF], wr[HID * OUTF];
    __shared__ float bb[OUTF];
    int t = threadIdx.x;
    for (int i = t; i < HID * OUTF; i += 512) {
        float a = W2[i];
        w20[i] = a;
        w2d[i] = W2[HID * OUTF + i] - a;
        wr[i] = root2[i];
    }
    if (t < OUTF) bb[t] = bias2[t];
    int b = blockIdx.x;
    int tot = gcur[b];
    int beg = b * CAP_REG;
    int nodeBase = b * BKT_NODES;
    if (t <= BKT_NODES) segb[t] = segg[b * (BKT_NODES + 1) + t];
    __syncthreads();

    if (tot <= CAP_LDS && segb[0] != -1) {
        for (int e = t; e < tot; e += 512) sbufL[e] = bkt[beg + e];
        __syncthreads();
        int j = t & (HID - 1);
        int g = t >> 4;
        int s = segb[2 * g], mid = segb[2 * g + 1], e2 = segb[2 * g + 2];
        float s00 = 0.f, s10 = 0.f, s01 = 0.f, s11 = 0.f;
        int e = s;
        for (; e + 8 <= mid; e += 8) {
            float hv[8], uv[8];
#pragma unroll
            for (int k = 0; k < 8; ++k) {
                int2 pk = sbufL[e + k];
                hv[k] = bfh(h16[(size_t)(pk.x & SRCM) * HID + j]);
                uv[k] = __int_as_float(pk.y);
            }
#pragma unroll
            for (int k = 0; k < 8; ++k) {
                s00 += hv[k];
                s10 = fmaf(uv[k], hv[k], s10);
            }
        }
        for (; e < mid; ++e) {
            int2 pk = sbufL[e];
            float hvv = bfh(h16[(size_t)(pk.x & SRCM) * HID + j]);
            s00 += hvv;
            s10 = fmaf(__int_as_float(pk.y), hvv, s10);
        }
        for (; e + 8 <= e2; e += 8) {
            float hv[8], uv[8];
#pragma unroll
            for (int k = 0; k < 8; ++k) {
                int2 pk = sbufL[e + k];
                hv[k] = bfh(h16[(size_t)(pk.x & SRCM) * HID + j]);
                uv[k] = __int_as_float(pk.y);
            }
#pragma unroll
            for (int k = 0; k < 8; ++k) {
                s01 += hv[k];
                s11 = fmaf(uv[k], hv[k], s11);
            }
        }
        for (; e < e2; ++e) {
            int2 pk = sbufL[e];
            float hvv = bfh(h16[(size_t)(pk.x & SRCM) * HID + j]);
            s01 += hvv;
            s11 = fmaf(__int_as_float(pk.y), hvv, s11);
        }
        s0L[(2 * g) * HID + j] = s00;
        s1L[(2 * g) * HID + j] = s10;
        s0L[(2 * g + 1) * HID + j] = s01;
        s1L[(2 * g + 1) * HID + j] = s11;
        __syncthreads();
    } else {
        int inreg = min(tot, CAP_REG);
        int end = beg + inreg;
        for (int i = t; i < BKT_NODES * HID; i += 512) { s0L[i] = 0.f; s1L[i] = 0.f; }
        __syncthreads();
        int j = t & (HID - 1);
        int g = t >> 4;
        for (int e = beg + g; e < end; e += 32) {
            int2 pk = bkt[e];
            float hvv = bfh(h16[(size_t)(pk.x & SRCM) * HID + j]);
            int l = ((unsigned)pk.x) >> 17;
            atomicAdd(&s0L[l * HID + j], hvv);
            atomicAdd(&s1L[l * HID + j], __int_as_float(pk.y) * hvv);
        }
        int ovn = min(novf[0], OVF_MAX);
        for (int o = 0; o < ovn; ++o) {
            int4 ent = ovf[o];
            int loc = ent.x - nodeBase;
            if (loc >= 0 && loc < BKT_NODES && g == 0) {
                float hvv = bfh(h16[(size_t)ent.y * HID + j]);
                atomicAdd(&s0L[loc * HID + j], hvv);
                atomicAdd(&s1L[loc * HID + j], __int_as_float(ent.z) * hvv);
            }
        }
        __syncthreads();
    }

#pragma unroll
    for (int it = 0; it < BKT_NODES * OUTF / 512; ++it) {  // 4
        int idx = it * 512 + t;
        int nl = idx >> 5, jj = idx & (OUTF - 1);
        int n = nodeBase + nl;
        float v = 0.f;
        if (n < NN) {
            float msum = 0.f;
            const float* S0 = &s0L[nl * HID];
            const float* S1 = &s1L[nl * HID];
#pragma unroll
            for (int f = 0; f < HID; ++f)
                msum += S0[f] * w20[f * OUTF + jj] + S1[f] * w2d[f * OUTF + jj];
            v = msum * dinv[n] + bb[jj];
            const unsigned short* hr = h16 + (size_t)n * HID;
#pragma unroll
            for (int f = 0; f < HID; ++f)
                v = fmaf(bfh(hr[f]), wr[f * OUTF + jj], v);
        }
        float m = v;
#pragma unroll
        for (int mask = 16; mask >= 1; mask >>= 1) m = fmaxf(m, __shfl_xor(m, mask));
        float ex = expf(v - m);
        float sm = ex;
#pragma unroll
        for (int mask = 16; mask >= 1; mask >>= 1) sm += __shfl_xor(sm, mask);
        if (n < NN) out[(size_t)n * OUTF + jj] = v - m - logf(sm);
    }
}

extern "C" void kernel_launch(void* const* d_in, const int* in_sizes, int n_in,
                              void* d_out, int out_size, void* d_ws, size_t ws_size,
                              hipStream_t stream) {
    const float* x     = (const float*)d_in[0];
    const int*   ei    = (const int*)d_in[1];
    const float* ea    = (const float*)d_in[3];
    const float* W1    = (const float*)d_in[4];
    const float* root1 = (const float*)d_in[5];
    const float* bias1 = (const float*)d_in[6];
    const float* W2    = (const float*)d_in[7];
    const float* root2 = (const float*)d_in[8];
    const float* bias2 = (const float*)d_in[9];
    float* out = (float*)d_out;
    float* ws  = (float*)d_ws;

    const size_t N = NN;
    int*            gcur = (int*)(ws);                        // 1563
    int*            novf = (int*)(ws + 2000);                 // 1
    int4*           ovf  = (int4*)(ws + 2048);                // OVF_MAX int4
    float*          dinv = ws + 20000;                        // 100000
    int*            segg = (int*)(ws + 120000);               // NBKT*65 = 101595
    float*          r1   = ws + 222000;                       // 16N
    unsigned*       ab1p = (unsigned*)(ws + 222000 + 16 * N); // 16N u32
    unsigned short* h16  = (unsigned short*)(ws + 222000 + 32 * N); // 16N u16
    int2*           bkt  = (int2*)(ws + 222000 + 40 * N);     // NBKT*CAP_REG int2

    int nbN = (NN + 255) / 256;
    zeroG_kernel<<<(NBKT + 256) / 256, 256, 0, stream>>>(gcur, novf);
    partF_kernel<<<PBLK2, 1024, 0, stream>>>(ei, ea, gcur, novf, ovf, bkt);
    proj1_kernel<<<nbN, 256, 0, stream>>>(x, W1, root1, bias1, ab1p, r1);
    gather1_kernel<<<NBKT, 512, 0, stream>>>(gcur, novf, ovf, bkt, ab1p, r1, h16, dinv, segg);
    gather2_kernel<<<NBKT, 512, 0, stream>>>(gcur, novf, ovf, bkt, h16, W2, root2, bias2, dinv, segg, out);
}

// Round 11
// 119.820 us; speedup vs baseline: 1.1527x; 1.0624x over previous
//
#include <hip/hip_runtime.h>
#include <math.h>

#define NN 100000
#define NE 1600000
#define F_IN 64
#define HID 16
#define OUTF 32
#define BKT_SHIFT 6
#define BKT_NODES 64
#define NBKT 1563               // ceil(NN/64)
#define SRCM 0x1FFFF
#define CAP_REG 2048            // fixed region per bucket (mean 1024, sd 32)
#define CAP_LDS 1536            // fast-path LDS sort capacity
#define PBLK2 500
#define EPB2 3200               // 500*3200 = 1.6M exact; 16B-aligned chunks
#define OVF_MAX 4096

__device__ __forceinline__ unsigned bf16r(float f) {   // round-to-nearest-even bf16 (finite)
    unsigned u = __float_as_uint(f);
    return (u + 0x7FFFu + ((u >> 16) & 1u)) >> 16;
}
__device__ __forceinline__ float bfa(unsigned p) { return __uint_as_float(p << 16); }
__device__ __forceinline__ float bfd(unsigned p) { return __uint_as_float(p & 0xFFFF0000u); }
__device__ __forceinline__ float bfh(unsigned short v) { return __uint_as_float(((unsigned)v) << 16); }

// accumulate 8 bf16 features (one uint4 of h16) into s0/s1
__device__ __forceinline__ void acc8(uint4 hv, float u, float* s0, float* s1) {
    unsigned w[4] = {hv.x, hv.y, hv.z, hv.w};
#pragma unroll
    for (int q = 0; q < 4; ++q) {
        float lo = __uint_as_float(w[q] << 16);
        float hi = __uint_as_float(w[q] & 0xFFFF0000u);
        s0[2 * q]     += lo; s1[2 * q]     = fmaf(u, lo, s1[2 * q]);
        s0[2 * q + 1] += hi; s1[2 * q + 1] = fmaf(u, hi, s1[2 * q + 1]);
    }
}
// accumulate 4 packed (a,d) features (one uint4 of ab1p)
__device__ __forceinline__ void acc4(uint4 ap, float u, float* a) {
    unsigned w[4] = {ap.x, ap.y, ap.z, ap.w};
#pragma unroll
    for (int q = 0; q < 4; ++q)
        a[q] += fmaf(u, bfd(w[q]), bfa(w[q]));
}

// ---- zero gcur/novf ----
__global__ __launch_bounds__(256) void zeroG_kernel(int* __restrict__ gcur,
                                                    int* __restrict__ novf) {
    int t = blockIdx.x * 256 + threadIdx.x;
    if (t < NBKT) gcur[t] = 0;
    if (t == NBKT) novf[0] = 0;
}

// ---- fused partition: vec-hist -> scan -> claim -> LDS-sorted stage -> coalesced writeout ----
__global__ __launch_bounds__(1024) void partF_kernel(const int* __restrict__ ei,
                                                     const float* __restrict__ ea,
                                                     int* __restrict__ gcur,
                                                     int* __restrict__ novf,
                                                     int4* __restrict__ ovf,
                                                     int2* __restrict__ bkt) {
    __shared__ int hcnt[NBKT];
    __shared__ int hbase[NBKT];
    __shared__ int lbase[NBKT];
    __shared__ int s[1024];
    __shared__ int2 sbuf[EPB2];                // 25.6 KB
    __shared__ unsigned short bid[EPB2];       // 6.4 KB
    int t = threadIdx.x, blk = blockIdx.x;
    for (int i = t; i < NBKT; i += 1024) hcnt[i] = 0;
    __syncthreads();
    int beg = blk * EPB2;
    int4 d4 = make_int4(0, 0, 0, 0);
    bool act = (4 * t) < EPB2;  // t < 800
    if (act) {
        d4 = *(const int4*)(ei + NE + beg + 4 * t);
        atomicAdd(&hcnt[d4.x >> BKT_SHIFT], 1);
        atomicAdd(&hcnt[d4.y >> BKT_SHIFT], 1);
        atomicAdd(&hcnt[d4.z >> BKT_SHIFT], 1);
        atomicAdd(&hcnt[d4.w >> BKT_SHIFT], 1);
    }
    __syncthreads();
    // exclusive scan of hcnt -> lbase
    int i0 = 2 * t, i1 = 2 * t + 1;
    int v0 = (i0 < NBKT) ? hcnt[i0] : 0;
    int v1 = (i1 < NBKT) ? hcnt[i1] : 0;
    s[t] = v0 + v1;
    __syncthreads();
    for (int off = 1; off < 1024; off <<= 1) {
        int xv = (t >= off) ? s[t - off] : 0;
        __syncthreads();
        s[t] += xv;
        __syncthreads();
    }
    int run = (t == 0) ? 0 : s[t - 1];
    if (i0 < NBKT) lbase[i0] = run;
    if (i1 < NBKT) lbase[i1] = run + v0;
    __syncthreads();
    for (int i = t; i < NBKT; i += 1024) {
        int c = hcnt[i];
        hbase[i] = c ? atomicAdd(&gcur[i], c) : 0;
        hcnt[i] = 0;
    }
    __syncthreads();
    if (act) {
        int4 s4 = *(const int4*)(ei + beg + 4 * t);
        float4 u4 = *(const float4*)(ea + beg + 4 * t);
        int dst[4] = {d4.x, d4.y, d4.z, d4.w};
        int src[4] = {s4.x, s4.y, s4.z, s4.w};
        float uu[4] = {u4.x, u4.y, u4.z, u4.w};
#pragma unroll
        for (int k = 0; k < 4; ++k) {
            int b = dst[k] >> BKT_SHIFT;
            int r = atomicAdd(&hcnt[b], 1);
            int lp = lbase[b] + r;
            sbuf[lp] = make_int2(src[k] | ((dst[k] & (BKT_NODES - 1)) << 17),
                                 __float_as_int(uu[k]));
            bid[lp] = (unsigned short)b;
        }
    }
    __syncthreads();
    for (int i = t; i < EPB2; i += 1024) {
        int2 pk = sbuf[i];
        int b = bid[i];
        int p = hbase[b] + (i - lbase[b]);
        if (p < CAP_REG) {
            bkt[(size_t)b * CAP_REG + p] = pk;
        } else {
            int o = atomicAdd(novf, 1);
            if (o < OVF_MAX)
                ovf[o] = make_int4(b * BKT_NODES + (((unsigned)pk.x) >> 17), pk.x & SRCM, pk.y, 0);
        }
    }
}

// ---- layer-1 projection: ab1p = pack_bf16(a, b-a); r1 = x@root1 + bias1 (fp32) ----
__global__ __launch_bounds__(256) void proj1_kernel(const float* __restrict__ x,
                                                    const float* __restrict__ W1,
                                                    const float* __restrict__ root1,
                                                    const float* __restrict__ bias1,
                                                    unsigned* __restrict__ ab1p,
                                                    float* __restrict__ r1) {
    __shared__ float w[2 * F_IN * HID];
    __shared__ float wr[F_IN * HID];
    __shared__ float bb[HID];
    for (int i = threadIdx.x; i < 2 * F_IN * HID; i += 256) w[i] = W1[i];
    for (int i = threadIdx.x; i < F_IN * HID; i += 256) wr[i] = root1[i];
    if (threadIdx.x < HID) bb[threadIdx.x] = bias1[threadIdx.x];
    __syncthreads();
    int n = blockIdx.x * 256 + threadIdx.x;
    if (n >= NN) return;
    float accA[HID], accB[HID], accR[HID];
#pragma unroll
    for (int o = 0; o < HID; ++o) { accA[o] = 0.f; accB[o] = 0.f; accR[o] = bb[o]; }
    const float4* xr4 = (const float4*)(x + (size_t)n * F_IN);
    for (int f4 = 0; f4 < F_IN / 4; ++f4) {
        float4 xv4 = xr4[f4];
        float xs[4] = {xv4.x, xv4.y, xv4.z, xv4.w};
#pragma unroll
        for (int q = 0; q < 4; ++q) {
            int f = f4 * 4 + q;
            float xv = xs[q];
            const float* w0 = &w[f * HID];
            const float* w1 = &w[F_IN * HID + f * HID];
            const float* w2 = &wr[f * HID];
#pragma unroll
            for (int o = 0; o < HID; ++o) {
                accA[o] = fmaf(xv, w0[o], accA[o]);
                accB[o] = fmaf(xv, w1[o], accB[o]);
                accR[o] = fmaf(xv, w2[o], accR[o]);
            }
        }
    }
    unsigned* ar = ab1p + (size_t)n * HID;
    float* rr = r1 + (size_t)n * HID;
#pragma unroll
    for (int o = 0; o < HID; ++o) {
        ar[o] = bf16r(accA[o]) | (bf16r(accB[o] - accA[o]) << 16);
        rr[o] = accR[o];
    }
}

// ---- layer-1: LDS sort + vectorized register accumulate + ELU -> h16; persist sorted+segg ----
__global__ __launch_bounds__(512) void gather1_kernel(const int* __restrict__ gcur,
                                                      const int* __restrict__ novf,
                                                      const int4* __restrict__ ovf,
                                                      int2* __restrict__ bkt,
                                                      const unsigned* __restrict__ ab1p,
                                                      const float* __restrict__ r1,
                                                      unsigned short* __restrict__ h16,
                                                      float* __restrict__ dinv,
                                                      int* __restrict__ segg) {
    __shared__ int2 raw[CAP_LDS];           // 12 KB
    __shared__ int2 sorted[CAP_LDS];        // 12 KB
    __shared__ int cnt[BKT_NODES], cur[BKT_NODES], segb[BKT_NODES + 1];
    __shared__ float degsL[BKT_NODES];
    int t = threadIdx.x;
    int b = blockIdx.x;
    int tot = gcur[b];
    int beg = b * CAP_REG;
    if (t < BKT_NODES) { cnt[t] = 0; cur[t] = 0; degsL[t] = 0.f; }
    __syncthreads();
    int nodeBase = b * BKT_NODES;

    if (tot <= CAP_LDS) {
        for (int e = t; e < tot; e += 512) raw[e] = bkt[beg + e];
        __syncthreads();
        for (int e = t; e < tot; e += 512)
            atomicAdd(&cnt[((unsigned)raw[e].x) >> 17], 1);
        __syncthreads();
        if (t < BKT_NODES) {
            int v = cnt[t];
            int sc = v;
#pragma unroll
            for (int off = 1; off < 64; off <<= 1) {
                int o = __shfl_up(sc, off, 64);
                if (t >= off) sc += o;
            }
            segb[t] = sc - v;
            if (t == 63) segb[64] = sc;
        }
        __syncthreads();
        for (int e = t; e < tot; e += 512) {
            int2 pk = raw[e];
            int loc = ((unsigned)pk.x) >> 17;
            int pos = segb[loc] + atomicAdd(&cur[loc], 1);
            sorted[pos] = pk;
        }
        __syncthreads();
        // persist sorted order + segment bounds for gather2
        for (int e = t; e < tot; e += 512) bkt[beg + e] = sorted[e];
        if (t <= BKT_NODES) segg[b * (BKT_NODES + 1) + t] = segb[t];
        // vectorized accumulate: 8 lanes/node = 2 edge-subsets x 4 feature-quarters
        int node = t >> 3;          // 0..63
        int sub = (t >> 2) & 1;     // edge subset
        int jq = t & 3;             // feature quarter (4 features)
        int s0 = segb[node], e2 = segb[node + 1];
        float acc[4] = {0.f, 0.f, 0.f, 0.f};
        int e = s0 + sub;
        for (; e + 2 < e2; e += 4) {
            int2 pkA = sorted[e];
            int2 pkB = sorted[e + 2];
            uint4 apA = *(const uint4*)(ab1p + ((size_t)(pkA.x & SRCM) << 4) + (jq << 2));
            uint4 apB = *(const uint4*)(ab1p + ((size_t)(pkB.x & SRCM) << 4) + (jq << 2));
            acc4(apA, __int_as_float(pkA.y), acc);
            acc4(apB, __int_as_float(pkB.y), acc);
        }
        if (e < e2) {
            int2 pk = sorted[e];
            uint4 ap = *(const uint4*)(ab1p + ((size_t)(pk.x & SRCM) << 4) + (jq << 2));
            acc4(ap, __int_as_float(pk.y), acc);
        }
#pragma unroll
        for (int k = 0; k < 4; ++k) acc[k] += __shfl_xor(acc[k], 4);
        if (sub == 0) {
            int n = nodeBase + node;
            if (n < NN) {
                float d0 = 1.f / (float)max(e2 - s0, 1);
                float4 rv = *(const float4*)(r1 + ((size_t)n << 4) + (jq << 2));
                float rr[4] = {rv.x, rv.y, rv.z, rv.w};
                unsigned hw[4];
#pragma unroll
                for (int k = 0; k < 4; ++k) {
                    float v = acc[k] * d0 + rr[k];
                    hw[k] = bf16r(v > 0.f ? v : expm1f(v));
                }
                *(uint2*)(h16 + ((size_t)n << 4) + (jq << 2)) =
                    make_uint2(hw[0] | (hw[1] << 16), hw[2] | (hw[3] << 16));
                if (jq == 0) dinv[n] = d0;
            }
        }
    } else {
        // ---- legacy atomic path (bucket overflow; statistically never) ----
        float* accL = (float*)raw;  // 1024 floats
        int inreg = min(tot, CAP_REG);
        int end = beg + inreg;
        for (int i = t; i < BKT_NODES * HID; i += 512) accL[i] = 0.f;
        __syncthreads();
        int j = t & (HID - 1);
        int g = t >> 4;
        for (int e = beg + g; e < end; e += 32) {
            int2 pk = bkt[e];
            unsigned p = ab1p[(size_t)(pk.x & SRCM) * HID + j];
            atomicAdd(&accL[(((unsigned)pk.x) >> 17) * HID + j],
                      fmaf(__int_as_float(pk.y), bfd(p), bfa(p)));
            if (j == 0) atomicAdd(&degsL[((unsigned)pk.x) >> 17], 1.f);
        }
        int ovn = min(novf[0], OVF_MAX);
        for (int o = 0; o < ovn; ++o) {
            int4 ent = ovf[o];
            int loc = ent.x - nodeBase;
            if (loc >= 0 && loc < BKT_NODES && g == 0) {
                unsigned p = ab1p[(size_t)ent.y * HID + j];
                atomicAdd(&accL[loc * HID + j], fmaf(__int_as_float(ent.z), bfd(p), bfa(p)));
                if (j == 0) atomicAdd(&degsL[loc], 1.f);
            }
        }
        __syncthreads();
        if (t < BKT_NODES) degsL[t] = 1.f / fmaxf(degsL[t], 1.f);
        if (t == 0) segg[b * (BKT_NODES + 1)] = -1;  // mark unsorted for gather2
        __syncthreads();
#pragma unroll
        for (int it = 0; it < BKT_NODES * HID / 512; ++it) {
            int idx = it * 512 + t;
            int nl = idx >> 4, jj = idx & (HID - 1);
            int n = nodeBase + nl;
            if (n < NN) {
                float v = accL[idx] * degsL[nl] + r1[(size_t)n * HID + jj];
                h16[(size_t)n * HID + jj] = (unsigned short)bf16r(v > 0.f ? v : expm1f(v));
            }
        }
        if (t < BKT_NODES && nodeBase + t < NN) dinv[nodeBase + t] = degsL[t];
    }
}

// ---- layer-2: vectorized S0=Σh, S1=Σu·h; project + root + log_softmax ----
__global__ __launch_bounds__(512) void gather2_kernel(const int* __restrict__ gcur,
                                                      const int* __restrict__ novf,
                                                      const int4* __restrict__ ovf,
                                                      const int2* __restrict__ bkt,
                                                      const unsigned short* __restrict__ h16,
                                                      const float* __restrict__ W2,
                                                      const float* __restrict__ root2,
                                                      const float* __restrict__ bias2,
                                                      const float* __restrict__ dinv,
                                                      const int* __restrict__ segg,
                                                      float* __restrict__ out) {
    __shared__ int2 sbufL[CAP_LDS];         // 12 KB
    __shared__ int segb[BKT_NODES + 1];
    __shared__ float s0L[BKT_NODES * HID];  // 4 KB
    __shared__ float s1L[BKT_NODES * HID];  // 4 KB
    __shared__ float hloc[BKT_NODES * HID]; // 4 KB (own-node h, f32)
    __shared__ float w20[HID * OUTF], w2d[HID * OUTF], wr[HID * OUTF];
    __shared__ float bb[OUTF];
    int t = threadIdx.x;
    for (int i = t; i < HID * OUTF; i += 512) {
        float a = W2[i];
        w20[i] = a;
        w2d[i] = W2[HID * OUTF + i] - a;
        wr[i] = root2[i];
    }
    if (t < OUTF) bb[t] = bias2[t];
    int b = blockIdx.x;
    int tot = gcur[b];
    int beg = b * CAP_REG;
    int nodeBase = b * BKT_NODES;
    if (t <= BKT_NODES) segb[t] = segg[b * (BKT_NODES + 1) + t];
    // stage own-node h rows (f32) for the root-term
    for (int i = t; i < BKT_NODES * HID; i += 512) {
        int n = nodeBase + (i >> 4);
        hloc[i] = (n < NN) ? bfh(h16[((size_t)nodeBase << 4) + i]) : 0.f;
    }
    __syncthreads();

    if (tot <= CAP_LDS && segb[0] != -1) {
        for (int e = t; e < tot; e += 512) sbufL[e] = bkt[beg + e];
        __syncthreads();
        // 8 lanes/node = 4 edge-subsets x 2 feature-halves
        int node = t >> 3;
        int sub = (t >> 1) & 3;
        int jh = t & 1;
        int s = segb[node], e2 = segb[node + 1];
        float s0[8] = {0.f, 0.f, 0.f, 0.f, 0.f, 0.f, 0.f, 0.f};
        float s1[8] = {0.f, 0.f, 0.f, 0.f, 0.f, 0.f, 0.f, 0.f};
        int e = s + sub;
        for (; e + 4 < e2; e += 8) {
            int2 pkA = sbufL[e];
            int2 pkB = sbufL[e + 4];
            uint4 hvA = *(const uint4*)(h16 + ((size_t)(pkA.x & SRCM) << 4) + (jh << 3));
            uint4 hvB = *(const uint4*)(h16 + ((size_t)(pkB.x & SRCM) << 4) + (jh << 3));
            acc8(hvA, __int_as_float(pkA.y), s0, s1);
            acc8(hvB, __int_as_float(pkB.y), s0, s1);
        }
        if (e < e2) {
            int2 pk = sbufL[e];
            uint4 hv = *(const uint4*)(h16 + ((size_t)(pk.x & SRCM) << 4) + (jh << 3));
            acc8(hv, __int_as_float(pk.y), s0, s1);
        }
#pragma unroll
        for (int k = 0; k < 8; ++k) {
            s0[k] += __shfl_xor(s0[k], 2); s0[k] += __shfl_xor(s0[k], 4);
            s1[k] += __shfl_xor(s1[k], 2); s1[k] += __shfl_xor(s1[k], 4);
        }
        if (sub == 0) {
            int base = node * HID + jh * 8;
#pragma unroll
            for (int k = 0; k < 8; ++k) { s0L[base + k] = s0[k]; s1L[base + k] = s1[k]; }
        }
        __syncthreads();
    } else {
        int inreg = min(tot, CAP_REG);
        int end = beg + inreg;
        for (int i = t; i < BKT_NODES * HID; i += 512) { s0L[i] = 0.f; s1L[i] = 0.f; }
        __syncthreads();
        int j = t & (HID - 1);
        int g = t >> 4;
        for (int e = beg + g; e < end; e += 32) {
            int2 pk = bkt[e];
            float hvv = bfh(h16[(size_t)(pk.x & SRCM) * HID + j]);
            int l = ((unsigned)pk.x) >> 17;
            atomicAdd(&s0L[l * HID + j], hvv);
            atomicAdd(&s1L[l * HID + j], __int_as_float(pk.y) * hvv);
        }
        int ovn = min(novf[0], OVF_MAX);
        for (int o = 0; o < ovn; ++o) {
            int4 ent = ovf[o];
            int loc = ent.x - nodeBase;
            if (loc >= 0 && loc < BKT_NODES && g == 0) {
                float hvv = bfh(h16[(size_t)ent.y * HID + j]);
                atomicAdd(&s0L[loc * HID + j], hvv);
                atomicAdd(&s1L[loc * HID + j], __int_as_float(ent.z) * hvv);
            }
        }
        __syncthreads();
    }

#pragma unroll
    for (int it = 0; it < BKT_NODES * OUTF / 512; ++it) {  // 4
        int idx = it * 512 + t;
        int nl = idx >> 5, jj = idx & (OUTF - 1);
        int n = nodeBase + nl;
        float v = 0.f;
        if (n < NN) {
            float msum = 0.f;
            const float* S0 = &s0L[nl * HID];
            const float* S1 = &s1L[nl * HID];
#pragma unroll
            for (int f = 0; f < HID; ++f)
                msum += S0[f] * w20[f * OUTF + jj] + S1[f] * w2d[f * OUTF + jj];
            v = msum * dinv[n] + bb[jj];
            const float* hr = &hloc[nl * HID];
#pragma unroll
            for (int f = 0; f < HID; ++f)
                v = fmaf(hr[f], wr[f * OUTF + jj], v);
        }
        float m = v;
#pragma unroll
        for (int mask = 16; mask >= 1; mask >>= 1) m = fmaxf(m, __shfl_xor(m, mask));
        float ex = expf(v - m);
        float sm = ex;
#pragma unroll
        for (int mask = 16; mask >= 1; mask >>= 1) sm += __shfl_xor(sm, mask);
        if (n < NN) out[(size_t)n * OUTF + jj] = v - m - logf(sm);
    }
}

extern "C" void kernel_launch(void* const* d_in, const int* in_sizes, int n_in,
                              void* d_out, int out_size, void* d_ws, size_t ws_size,
                              hipStream_t stream) {
    const float* x     = (const float*)d_in[0];
    const int*   ei    = (const int*)d_in[1];
    const float* ea    = (const float*)d_in[3];
    const float* W1    = (const float*)d_in[4];
    const float* root1 = (const float*)d_in[5];
    const float* bias1 = (const float*)d_in[6];
    const float* W2    = (const float*)d_in[7];
    const float* root2 = (const float*)d_in[8];
    const float* bias2 = (const float*)d_in[9];
    float* out = (float*)d_out;
    float* ws  = (float*)d_ws;

    const size_t N = NN;
    int*            gcur = (int*)(ws);                        // 1563
    int*            novf = (int*)(ws + 2000);                 // 1
    int4*           ovf  = (int4*)(ws + 2048);                // OVF_MAX int4
    float*          dinv = ws + 20000;                        // 100000
    int*            segg = (int*)(ws + 120000);               // NBKT*65 = 101595
    float*          r1   = ws + 222000;                       // 16N
    unsigned*       ab1p = (unsigned*)(ws + 222000 + 16 * N); // 16N u32
    unsigned short* h16  = (unsigned short*)(ws + 222000 + 32 * N); // 16N u16
    int2*           bkt  = (int2*)(ws + 222000 + 40 * N);     // NBKT*CAP_REG int2

    int nbN = (NN + 255) / 256;
    zeroG_kernel<<<(NBKT + 256) / 256, 256, 0, stream>>>(gcur, novf);
    partF_kernel<<<PBLK2, 1024, 0, stream>>>(ei, ea, gcur, novf, ovf, bkt);
    proj1_kernel<<<nbN, 256, 0, stream>>>(x, W1, root1, bias1, ab1p, r1);
    gather1_kernel<<<NBKT, 512, 0, stream>>>(gcur, novf, ovf, bkt, ab1p, r1, h16, dinv, segg);
    gather2_kernel<<<NBKT, 512, 0, stream>>>(gcur, novf, ovf, bkt, h16, W2, root2, bias2, dinv, segg, out);
}